// Round 6
// baseline (255.155 us; speedup 1.0000x reference)
//
#include <hip/hip_runtime.h>

typedef short short8 __attribute__((ext_vector_type(8)));
typedef float f32x4 __attribute__((ext_vector_type(4)));
typedef float f32x16 __attribute__((ext_vector_type(16)));
typedef unsigned short u16x4 __attribute__((ext_vector_type(4)));

constexpr int NB = 16, CIN = 128, LIN = 2048, CO = 256;
constexpr int SL = 2041;                 // output sequence length
constexpr int MT = NB * SL;              // 32656 valid rows
constexpr int MP = 32768;                // padded rows
constexpr int XTS = 136;                 // xT row stride (elems): 16B-aligned

// ---- workspace layout (bytes, all 256-aligned) ----
constexpr size_t XT_OFF = 0;
constexpr size_t XT_SZ  = (size_t)NB*LIN*XTS*2 + 65536;  // bf16 xT [n][s][136] + OOB slack
constexpr size_t CW_OFF = XT_OFF + XT_SZ;
constexpr size_t CW_SZ  = (size_t)CO*CIN*8*2;            // conv_w bf16 [256][1024], kk=kp*128+ci
constexpr size_t WQ_OFF = CW_OFF + CW_SZ;
constexpr size_t WB_SZ  = (size_t)CO*CO*2;
constexpr size_t WK_OFF = WQ_OFF + WB_SZ;
constexpr size_t WV_OFF = WK_OFF + WB_SZ;
constexpr size_t H_OFF  = WV_OFF + WB_SZ;
constexpr size_t HB_SZ  = (size_t)MP*CO*2;               // 16 MB each
constexpr size_t Q_OFF  = H_OFF + HB_SZ;
constexpr size_t K_OFF  = Q_OFF + HB_SZ;
constexpr size_t VT_OFF = K_OFF + HB_SZ;                 // v transposed [256][16][2048]

__device__ inline unsigned short f2bf(float f) {
  union { float f; unsigned int u; } v; v.f = f;
  unsigned int r = v.u + 0x7fffu + ((v.u >> 16) & 1u);
  return (unsigned short)(r >> 16);
}

// CK-style LDS barrier: waits only lgkmcnt(0) (ds ops), does NOT drain vmcnt.
__device__ inline void sync_lds() {
  __asm__ volatile("" ::: "memory");
  __builtin_amdgcn_s_waitcnt(0xc07f);   // lgkmcnt(0)
  __builtin_amdgcn_s_barrier();
  __asm__ volatile("" ::: "memory");
}
__device__ inline void barrier_only() {
  __asm__ volatile("" ::: "memory");
  __builtin_amdgcn_s_barrier();
  __asm__ volatile("" ::: "memory");
}

#if defined(__has_builtin)
#if __has_builtin(__builtin_amdgcn_global_load_lds)
#define HAVE_GLDS 1
#endif
#endif

__device__ inline void gld16(const unsigned short* g, void* l) {
#ifdef HAVE_GLDS
  __builtin_amdgcn_global_load_lds(
      (const __attribute__((address_space(1))) void*)g,
      (__attribute__((address_space(3))) void*)l, 16, 0, 0);
#else
  *(short8*)l = *(const short8*)g;
#endif
}

// ---------------- fused prep: xpose (4096 blk) + wconv (1024 blk) + wqkv (192 blk) ---------
// One launch instead of three (independent outputs; consumers are downstream kernels).
__global__ __launch_bounds__(256) void prep_kernel(
    const float* __restrict__ x, unsigned short* __restrict__ xt,
    const float* __restrict__ cw_in, unsigned short* __restrict__ cw_out,
    const float* __restrict__ wq, const float* __restrict__ wk, const float* __restrict__ wv,
    unsigned short* __restrict__ wqb, unsigned short* __restrict__ wkb,
    unsigned short* __restrict__ wvb) {
  __shared__ float tile[32][33];
  const int b = blockIdx.x;
  const int tid = threadIdx.x;
  if (b < 4096) {
    // x transpose + bf16: [16][128][2048] f32 -> [16][2048][136] bf16
    const int tx = tid & 31, ty = tid >> 5;
    const int s0 = (b & 63) * 32, c0 = ((b >> 6) & 3) * 32, n = b >> 8;
    #pragma unroll
    for (int r = 0; r < 4; ++r)
      tile[ty * 4 + r][tx] = x[((size_t)(n * CIN + c0 + ty * 4 + r)) * LIN + s0 + tx];
    __syncthreads();
    #pragma unroll
    for (int r = 0; r < 4; ++r)
      xt[((size_t)(n * LIN + s0 + ty * 4 + r)) * XTS + c0 + tx] = f2bf(tile[tx][ty * 4 + r]);
  } else if (b < 4096 + 1024) {
    // conv weight reorder: [256][128][8] f32 -> bf16 [256][1024], kk = kp*128+ci
    int idx = (b - 4096) * 256 + tid;
    int co = idx >> 10, r = idx & 1023, kp = r >> 7, ci = r & 127;
    cw_out[idx] = f2bf(cw_in[co * 1024 + ci * 8 + kp]);
  } else {
    // q/k/v weight f32 -> bf16
    int lb2 = b - (4096 + 1024);
    int z = lb2 >> 6, lb = lb2 & 63;
    const float* src = (z == 0) ? wq : (z == 1) ? wk : wv;
    unsigned short* dst = (z == 0) ? wqb : (z == 1) ? wkb : wvb;
    int i = (lb * 256 + tid) * 4;
    float4 v = *(const float4*)(src + i);
    u16x4 r;
    r.x = f2bf(v.x); r.y = f2bf(v.y); r.z = f2bf(v.z); r.w = f2bf(v.w);
    *(u16x4*)(dst + i) = r;
  }
}

// ---------------- conv as implicit GEMM: reg-prefetch dbuf weights ----------------
__global__ __launch_bounds__(256) void conv_gemm(
    const unsigned short* __restrict__ xt,   // [16][2048][136] bf16
    const unsigned short* __restrict__ wb,   // [256][1024] bf16 (kk = kp*128+ci)
    const float* __restrict__ bias,
    unsigned short* __restrict__ h)          // [MP][256] bf16
{
  __shared__ unsigned short sX[18432];       // 36 KB x-window
  __shared__ unsigned short sB[2][4096];     // 2 x 8 KB weight chunk, chunk-swizzled
  const int tid = threadIdx.x;
  const int w = tid >> 6, lane = tid & 63, quad = lane >> 4, l16 = lane & 15;
  const int n  = blockIdx.y;
  const int s0 = blockIdx.x * 128;
  const int d0 = blockIdx.z * 128;

  {
    const unsigned short* xbase = xt + ((size_t)n * LIN + s0) * XTS;
    #pragma unroll
    for (int i = 0; i < 9; ++i) {
      int u = i * 256 + tid;
      gld16(xbase + u * 8, ((char*)sX) + u * 16);
    }
  }

  const int brow0 = tid >> 2, bkgs = tid & 3;
  short8 breg[2];
  #pragma unroll
  for (int i2 = 0; i2 < 2; ++i2) {
    int row = i2 * 64 + brow0;
    int kg = bkgs ^ ((row >> 1) & 3);
    breg[i2] = *(const short8*)(wb + (size_t)(d0 + row) * 1024 + kg * 8);
  }
  #pragma unroll
  for (int i2 = 0; i2 < 2; ++i2)
    *(short8*)(&sB[0][(i2 * 256 + tid) * 8]) = breg[i2];
  __syncthreads();                          // full drain once (X DMA + sB[0])

  f32x4 acc[2][8];
  #pragma unroll
  for (int i = 0; i < 2; ++i)
    #pragma unroll
    for (int j = 0; j < 8; ++j) acc[i][j] = (f32x4){0.f, 0.f, 0.f, 0.f};

  for (int kc = 0; kc < 32; ++kc) {
    const int kcn = (kc < 31) ? kc + 1 : kc;
    const int kpn = kcn >> 2, ci0n = (kcn & 3) * 32;
    #pragma unroll
    for (int i2 = 0; i2 < 2; ++i2) {
      int row = i2 * 64 + brow0;
      int kg = bkgs ^ ((row >> 1) & 3);
      breg[i2] = *(const short8*)(wb + (size_t)(d0 + row) * 1024 + kpn * 128 + ci0n + kg * 8);
    }

    const int kp = kc >> 2, ci0 = (kc & 3) * 32;
    const unsigned short* sBc = sB[kc & 1];
    short8 bfr[8];
    #pragma unroll
    for (int j = 0; j < 8; ++j) {
      int r = j * 16 + l16;
      bfr[j] = *(const short8*)(sBc + r * 32 + (quad ^ ((r >> 1) & 3)) * 8);
    }
    #pragma unroll
    for (int i = 0; i < 2; ++i) {
      int srow = w * 32 + i * 16 + l16;
      short8 afr = *(const short8*)(sX + (srow + kp) * XTS + ci0 + quad * 8);
      #pragma unroll
      for (int j = 0; j < 8; ++j)
        acc[i][j] = __builtin_amdgcn_mfma_f32_16x16x32_bf16(afr, bfr[j], acc[i][j], 0, 0, 0);
    }

    #pragma unroll
    for (int i2 = 0; i2 < 2; ++i2)
      *(short8*)(&sB[(kc + 1) & 1][(i2 * 256 + tid) * 8]) = breg[i2];
    sync_lds();
  }

  #pragma unroll
  for (int i = 0; i < 2; ++i)
    #pragma unroll
    for (int j = 0; j < 8; ++j) {
      int col = d0 + j * 16 + l16;
      float bv = bias[col];
      #pragma unroll
      for (int jj = 0; jj < 4; ++jj) {
        int s = s0 + w * 32 + i * 16 + quad * 4 + jj;
        if (s < SL) {
          float val = fmaxf(acc[i][j][jj] + bv, 0.f);
          h[(size_t)(n * SL + s) * CO + col] = f2bf(val);
        }
      }
    }
}

// ---------------- q/k/v linear GEMMs: reg-prefetch dbuf A and B ----------------
__global__ __launch_bounds__(256) void lin_gemm(
    const unsigned short* __restrict__ A,    // h [MP][256]
    const unsigned short* __restrict__ Bq, const unsigned short* __restrict__ Bk,
    const unsigned short* __restrict__ Bv,
    const float* __restrict__ biq, const float* __restrict__ bik,
    const float* __restrict__ biv,
    unsigned short* __restrict__ qb, unsigned short* __restrict__ kb,
    unsigned short* __restrict__ vtb)
{
  __shared__ unsigned short sA[2][4096];
  __shared__ unsigned short sB[2][4096];
  const int tid = threadIdx.x;
  const int w = tid >> 6, lane = tid & 63, quad = lane >> 4, l16 = lane & 15;
  const int m0 = blockIdx.x * 128, d0 = blockIdx.y * 128, z = blockIdx.z;
  const unsigned short* B = (z == 0) ? Bq : (z == 1) ? Bk : Bv;
  const float* bias        = (z == 0) ? biq : (z == 1) ? bik : biv;

  const int brow0 = tid >> 2, bkgs = tid & 3;
  short8 areg[2], breg[2];
  #pragma unroll
  for (int i2 = 0; i2 < 2; ++i2) {
    int row = i2 * 64 + brow0;
    int kg = bkgs ^ ((row >> 1) & 3);
    areg[i2] = *(const short8*)(A + (size_t)(m0 + row) * CO + kg * 8);
    breg[i2] = *(const short8*)(B + (size_t)(d0 + row) * CO + kg * 8);
  }
  #pragma unroll
  for (int i2 = 0; i2 < 2; ++i2) {
    *(short8*)(&sA[0][(i2 * 256 + tid) * 8]) = areg[i2];
    *(short8*)(&sB[0][(i2 * 256 + tid) * 8]) = breg[i2];
  }
  sync_lds();

  f32x4 acc[2][8];
  #pragma unroll
  for (int i = 0; i < 2; ++i)
    #pragma unroll
    for (int j = 0; j < 8; ++j) acc[i][j] = (f32x4){0.f, 0.f, 0.f, 0.f};

  for (int kc = 0; kc < 8; ++kc) {
    const int kcn = (kc < 7) ? kc + 1 : kc;
    #pragma unroll
    for (int i2 = 0; i2 < 2; ++i2) {
      int row = i2 * 64 + brow0;
      int kg = bkgs ^ ((row >> 1) & 3);
      areg[i2] = *(const short8*)(A + (size_t)(m0 + row) * CO + kcn * 32 + kg * 8);
      breg[i2] = *(const short8*)(B + (size_t)(d0 + row) * CO + kcn * 32 + kg * 8);
    }

    const unsigned short* sAc = sA[kc & 1];
    const unsigned short* sBc = sB[kc & 1];
    short8 afr[2], bfr[8];
    #pragma unroll
    for (int i = 0; i < 2; ++i) {
      int r = w * 32 + i * 16 + l16;
      afr[i] = *(const short8*)(sAc + r * 32 + (quad ^ ((r >> 1) & 3)) * 8);
    }
    #pragma unroll
    for (int j = 0; j < 8; ++j) {
      int r = j * 16 + l16;
      bfr[j] = *(const short8*)(sBc + r * 32 + (quad ^ ((r >> 1) & 3)) * 8);
    }
    #pragma unroll
    for (int i = 0; i < 2; ++i)
      #pragma unroll
      for (int j = 0; j < 8; ++j)
        acc[i][j] = __builtin_amdgcn_mfma_f32_16x16x32_bf16(afr[i], bfr[j], acc[i][j], 0, 0, 0);

    #pragma unroll
    for (int i2 = 0; i2 < 2; ++i2) {
      *(short8*)(&sA[(kc + 1) & 1][(i2 * 256 + tid) * 8]) = areg[i2];
      *(short8*)(&sB[(kc + 1) & 1][(i2 * 256 + tid) * 8]) = breg[i2];
    }
    sync_lds();
  }

  #pragma unroll
  for (int i = 0; i < 2; ++i)
    #pragma unroll
    for (int j = 0; j < 8; ++j) {
      int col = d0 + j * 16 + l16;
      float bv = bias[col];
      #pragma unroll
      for (int jj = 0; jj < 4; ++jj) {
        int m = m0 + w * 32 + i * 16 + quad * 4 + jj;
        float val = acc[i][j][jj] + bv;
        if (z < 2) {
          ((z == 0) ? qb : kb)[(size_t)m * CO + col] = f2bf(val);
        } else if (m < MT) {
          int nn = m / SL, ss = m - nn * SL;
          vtb[(size_t)col * MP + nn * 2048 + ss] = f2bf(val);
        }
      }
    }
}

// ---------------- fused sigmoid attention: deferred-PV pipeline, 1 barrier/iter ----------
// grid 256, 512 threads = 8 waves (sr=w&3 s-range, tr=w>>2 t/d-half), s-tile 128, t-tile 64.
// LDS (160 KB = per-CU max, AITER fmha precedent): sK[2] 64 KB, sV[2] 64 KB, sP[2] 32 KB.
// Round-5 analysis: 7.7K cyc/iter measured vs ~3.5K busiest-pipe (LDS) -> ~4K cyc/iter lost
// to 3 block-wide barriers + serial sigmoid phase. Fix: double-buffer sP and DEFER PV by one
// t-tile. Per iter it: stage K(it+1)->sK[cur^1], V(it)->sV[cur]; QK(it) from sK[cur];
// PV(it-1) from sP[cur^1]+sV[cur^1]; sigmoid(it)+P-write -> sP[cur]; ONE vmcnt(0)+barrier.
// P-writes/P-reads hit different buffers -> the write->read barrier disappears (96 -> 33).
// Numerics identical (PV order still t-ascending, shifted one iter).
__global__ __launch_bounds__(512, 2) void attn_kernel(
    const unsigned short* __restrict__ qb,   // [MP][256]
    const unsigned short* __restrict__ kb,   // [MP][256]
    const unsigned short* __restrict__ vtb,  // [256][16][2048]
    float* __restrict__ out)                 // [16][256][2041]
{
  __shared__ unsigned short sK[2][16384];    // 2 x 32 KB
  __shared__ unsigned short sV[2][16384];    // 2 x 32 KB
  __shared__ unsigned short sP[2][8192];     // 2 x 16 KB
  const int tid = threadIdx.x;
  const int w = tid >> 6, lane = tid & 63;
  const int half = lane >> 5, l32 = lane & 31;
  const int bidx = blockIdx.x;
  const int n = (bidx & 7) + ((bidx >> 7) << 3);   // XCD-pinned: 2 n's per XCD
  const int s0 = ((bidx >> 3) & 15) * 128;
  const int sr = w & 3, tr = w >> 2;         // tr doubles as d-half in PV

  const unsigned short* kbN = kb + (size_t)(n * SL) * CO;
  const unsigned short* vbN = vtb + (size_t)n * 2048;

  // K: u = i*512+tid -> t = u>>5, slot = u&31; cell holds global chunk slot^(t&31).
  // V: u -> d = u>>3, slot = u&7; cell holds global t-chunk slot^(d&7).
#define STAGE_K(buf, tk)                                                         \
  {                                                                              \
    _Pragma("unroll")                                                            \
    for (int i = 0; i < 4; ++i) {                                                \
      int u = i * 512 + tid;                                                     \
      int t = u >> 5, sl = u & 31;                                               \
      gld16(kbN + (size_t)((tk) + t) * CO + ((sl ^ (t & 31)) << 3),              \
            ((char*)sK[buf]) + u * 16);                                          \
    }                                                                            \
  }
#define STAGE_V(buf, tk)                                                         \
  {                                                                              \
    _Pragma("unroll")                                                            \
    for (int i = 0; i < 4; ++i) {                                                \
      int u = i * 512 + tid;                                                     \
      int d = u >> 3, sl = u & 7;                                                \
      gld16(vbN + (size_t)d * MP + (tk) + ((sl ^ (d & 7)) << 3),                 \
            ((char*)sV[buf]) + u * 16);                                          \
    }                                                                            \
  }

  STAGE_K(0, 0)

  // Q frags (B-operand): element (s = s0+sr*32+l32, c = kk*16+half*8+j)
  short8 qf[16];
  {
    const unsigned short* qp = qb + (size_t)(n * SL + s0 + sr * 32 + l32) * CO + half * 8;
    #pragma unroll
    for (int kk = 0; kk < 16; ++kk) qf[kk] = *(const short8*)(qp + kk * 16);
  }

  __builtin_amdgcn_s_waitcnt(0x0F70);        // vmcnt(0): K tile0 + Q resident
  barrier_only();

  f32x16 o[4];
  #pragma unroll
  for (int di = 0; di < 4; ++di)
    #pragma unroll
    for (int r = 0; r < 16; ++r) o[di][r] = 0.f;

  for (int it = 0; it <= 32; ++it) {
    const int cur = it & 1;
    // stage K for tile it+1 and V for tile it (both read next iter; waited at iter end)
    if (it < 31) STAGE_K(cur ^ 1, (it + 1) * 64)
    if (it < 32) STAGE_V(cur, it * 64)

    // QK^T(it) as mfma(kf, qf) from sK[cur]: C col = s (lane), rows = t
    f32x16 sacc;
    if (it < 32) {
      const unsigned short* sKc = sK[cur];
      const int tl = tr * 32 + l32;
      #pragma unroll
      for (int r = 0; r < 16; ++r) sacc[r] = 0.f;
      __builtin_amdgcn_s_setprio(1);
      #pragma unroll
      for (int kk = 0; kk < 16; ++kk) {
        short8 kf = *(const short8*)(sKc + tl * 256 + (((kk * 2 + half) ^ (tl & 31)) << 3));
        sacc = __builtin_amdgcn_mfma_f32_32x32x16_bf16(kf, qf[kk], sacc, 0, 0, 0);
      }
      __builtin_amdgcn_s_setprio(0);
    }

    // PV(it-1): A rows = d, B cols = s; reads PREVIOUS buffers (no barrier needed vs writes)
    if (it >= 1) {
      const unsigned short* sVp = sV[cur ^ 1];
      const unsigned short* sPp = sP[cur ^ 1];
      __builtin_amdgcn_s_setprio(1);
      #pragma unroll
      for (int kt = 0; kt < 4; ++kt) {
        int g = kt * 2 + half;
        short8 pa = *(const short8*)(sPp + ((g << 7) + sr * 32 + l32) * 8);
        #pragma unroll
        for (int di = 0; di < 4; ++di) {
          int d = tr * 128 + di * 32 + l32;
          short8 vf = *(const short8*)(sVp + d * 64 + ((g ^ (d & 7)) << 3));
          o[di] = __builtin_amdgcn_mfma_f32_32x32x16_bf16(vf, pa, o[di], 0, 0, 0);
        }
      }
      __builtin_amdgcn_s_setprio(0);
    }

    // sigmoid(it) + packed P-write into sP[cur] (read by PV at iter it+1)
    if (it < 32) {
      const int t0 = it * 64;
      #pragma unroll
      for (int q2 = 0; q2 < 4; ++q2) {
        u16x4 pk;
        #pragma unroll
        for (int e = 0; e < 4; ++e) {
          int tg = t0 + tr * 32 + 8 * q2 + 4 * half + e;
          float p = __builtin_amdgcn_rcpf(1.f + __expf(-sacc[q2 * 4 + e] * 0.0625f));
          pk[e] = (tg < SL) ? f2bf(p) : (unsigned short)0;
        }
        *(u16x4*)(sP[cur] + ((tr * 4 + q2) * 128 + sr * 32 + l32) * 8 + 4 * half) = pk;
      }
    }

    // single rendezvous: this iter's DMAs landed + all ds ops drained
    if (it < 32) {
      __builtin_amdgcn_s_waitcnt(0x0F70);    // vmcnt(0): K(it+1) + V(it) resident
      sync_lds();
    }
  }

  // store: C col = s = s0+sr*32+l32 (coalesced 32-lane runs), rows = d
  const int s = s0 + sr * 32 + l32;
  if (s < SL) {
    float* op = out + (size_t)n * CO * SL + s;
    #pragma unroll
    for (int di = 0; di < 4; ++di)
      #pragma unroll
      for (int r = 0; r < 16; ++r) {
        int d = tr * 128 + di * 32 + (r & 3) + 8 * (r >> 2) + 4 * half;
        __builtin_nontemporal_store(o[di][r], op + (size_t)d * SL);
      }
  }
#undef STAGE_K
#undef STAGE_V
}

extern "C" void kernel_launch(void* const* d_in, const int* in_sizes, int n_in,
                              void* d_out, int out_size, void* d_ws, size_t ws_size,
                              hipStream_t stream) {
  const float* x      = (const float*)d_in[0];
  const float* conv_w = (const float*)d_in[1];
  const float* conv_b = (const float*)d_in[2];
  const float* wq     = (const float*)d_in[3];
  const float* bq     = (const float*)d_in[4];
  const float* wk     = (const float*)d_in[5];
  const float* bk     = (const float*)d_in[6];
  const float* wv     = (const float*)d_in[7];
  const float* bv     = (const float*)d_in[8];

  char* ws = (char*)d_ws;
  unsigned short* xt  = (unsigned short*)(ws + XT_OFF);
  unsigned short* cw  = (unsigned short*)(ws + CW_OFF);
  unsigned short* wqb = (unsigned short*)(ws + WQ_OFF);
  unsigned short* wkb = (unsigned short*)(ws + WK_OFF);
  unsigned short* wvb = (unsigned short*)(ws + WV_OFF);
  unsigned short* hb  = (unsigned short*)(ws + H_OFF);
  unsigned short* qb  = (unsigned short*)(ws + Q_OFF);
  unsigned short* kb  = (unsigned short*)(ws + K_OFF);
  unsigned short* vtb = (unsigned short*)(ws + VT_OFF);

  hipLaunchKernelGGL(prep_kernel, dim3(4096 + 1024 + 192), dim3(256), 0, stream,
                     x, xt, conv_w, cw, wq, wk, wv, wqb, wkb, wvb);
  hipLaunchKernelGGL(conv_gemm, dim3(16, 16, 2), dim3(256), 0, stream, xt, cw, conv_b, hb);
  hipLaunchKernelGGL(lin_gemm,  dim3(256, 2, 3), dim3(256), 0, stream,
                     hb, wqb, wkb, wvb, bq, bk, bv, qb, kb, vtb);
  hipLaunchKernelGGL(attn_kernel, dim3(256), dim3(512), 0, stream,
                     qb, kb, vtb, (float*)d_out);
}

// Round 7
// 233.457 us; speedup vs baseline: 1.0929x; 1.0929x over previous
//
#include <hip/hip_runtime.h>

typedef short short8 __attribute__((ext_vector_type(8)));
typedef float f32x4 __attribute__((ext_vector_type(4)));
typedef float f32x16 __attribute__((ext_vector_type(16)));
typedef unsigned short u16x4 __attribute__((ext_vector_type(4)));

constexpr int NB = 16, CIN = 128, LIN = 2048, CO = 256;
constexpr int SL = 2041;                 // output sequence length
constexpr int MP = 32768;                // padded rows = 16 * 2048 (s padded to 2048 per n)
constexpr int XTS = 136;                 // xT row stride (elems): 16B-aligned

// Row index convention (round-6 change): m = n*2048 + s  (NOT n*SL+s).
// Padded rows s in [SL,2048) carry garbage through h/q/k; all consumers mask:
//   - K garbage -> sigmoid -> P masked to 0 by (tg < SL) ternary (post-NaN-safe)
//   - vtb tail ss in [SL,2048) explicitly ZEROED at write (PV reads 0, never NaN)
//   - q rows >= SL never read (attn s < SL always)

// ---- workspace layout (bytes, all 256-aligned) ----
constexpr size_t XT_OFF = 0;
constexpr size_t XT_SZ  = (size_t)NB*LIN*XTS*2 + 65536;  // bf16 xT [n][s][136] + OOB slack
constexpr size_t CW_OFF = XT_OFF + XT_SZ;
constexpr size_t CW_SZ  = (size_t)CO*CIN*8*2;            // conv_w bf16 [256][1024], kk=kp*128+ci
constexpr size_t WQ_OFF = CW_OFF + CW_SZ;
constexpr size_t WB_SZ  = (size_t)CO*CO*2;
constexpr size_t WK_OFF = WQ_OFF + WB_SZ;
constexpr size_t WV_OFF = WK_OFF + WB_SZ;
constexpr size_t H_OFF  = WV_OFF + WB_SZ;
constexpr size_t HB_SZ  = (size_t)MP*CO*2;               // 16 MB each
constexpr size_t Q_OFF  = H_OFF + HB_SZ;
constexpr size_t K_OFF  = Q_OFF + HB_SZ;
constexpr size_t VT_OFF = K_OFF + HB_SZ;                 // v transposed [256][16][2048]

__device__ inline unsigned short f2bf(float f) {
  union { float f; unsigned int u; } v; v.f = f;
  unsigned int r = v.u + 0x7fffu + ((v.u >> 16) & 1u);
  return (unsigned short)(r >> 16);
}

// CK-style LDS barrier: waits only lgkmcnt(0) (ds ops), does NOT drain vmcnt.
__device__ inline void sync_lds() {
  __asm__ volatile("" ::: "memory");
  __builtin_amdgcn_s_waitcnt(0xc07f);   // lgkmcnt(0)
  __builtin_amdgcn_s_barrier();
  __asm__ volatile("" ::: "memory");
}
__device__ inline void barrier_only() {
  __asm__ volatile("" ::: "memory");
  __builtin_amdgcn_s_barrier();
  __asm__ volatile("" ::: "memory");
}

#if defined(__has_builtin)
#if __has_builtin(__builtin_amdgcn_global_load_lds)
#define HAVE_GLDS 1
#endif
#endif

__device__ inline void gld16(const unsigned short* g, void* l) {
#ifdef HAVE_GLDS
  __builtin_amdgcn_global_load_lds(
      (const __attribute__((address_space(1))) void*)g,
      (__attribute__((address_space(3))) void*)l, 16, 0, 0);
#else
  *(short8*)l = *(const short8*)g;
#endif
}

// ---------------- fused prep: xpose (4096 blk) + wconv (1024 blk) + wqkv (192 blk) ---------
__global__ __launch_bounds__(256) void prep_kernel(
    const float* __restrict__ x, unsigned short* __restrict__ xt,
    const float* __restrict__ cw_in, unsigned short* __restrict__ cw_out,
    const float* __restrict__ wq, const float* __restrict__ wk, const float* __restrict__ wv,
    unsigned short* __restrict__ wqb, unsigned short* __restrict__ wkb,
    unsigned short* __restrict__ wvb) {
  __shared__ float tile[32][33];
  const int b = blockIdx.x;
  const int tid = threadIdx.x;
  if (b < 4096) {
    const int tx = tid & 31, ty = tid >> 5;
    const int s0 = (b & 63) * 32, c0 = ((b >> 6) & 3) * 32, n = b >> 8;
    #pragma unroll
    for (int r = 0; r < 4; ++r)
      tile[ty * 4 + r][tx] = x[((size_t)(n * CIN + c0 + ty * 4 + r)) * LIN + s0 + tx];
    __syncthreads();
    #pragma unroll
    for (int r = 0; r < 4; ++r)
      xt[((size_t)(n * LIN + s0 + ty * 4 + r)) * XTS + c0 + tx] = f2bf(tile[tx][ty * 4 + r]);
  } else if (b < 4096 + 1024) {
    int idx = (b - 4096) * 256 + tid;
    int co = idx >> 10, r = idx & 1023, kp = r >> 7, ci = r & 127;
    cw_out[idx] = f2bf(cw_in[co * 1024 + ci * 8 + kp]);
  } else {
    int lb2 = b - (4096 + 1024);
    int z = lb2 >> 6, lb = lb2 & 63;
    const float* src = (z == 0) ? wq : (z == 1) ? wk : wv;
    unsigned short* dst = (z == 0) ? wqb : (z == 1) ? wkb : wvb;
    int i = (lb * 256 + tid) * 4;
    float4 v = *(const float4*)(src + i);
    u16x4 r;
    r.x = f2bf(v.x); r.y = f2bf(v.y); r.z = f2bf(v.z); r.w = f2bf(v.w);
    *(u16x4*)(dst + i) = r;
  }
}

// ---------------- conv as implicit GEMM: reg-prefetch dbuf weights ----------------
__global__ __launch_bounds__(256) void conv_gemm(
    const unsigned short* __restrict__ xt,   // [16][2048][136] bf16
    const unsigned short* __restrict__ wb,   // [256][1024] bf16 (kk = kp*128+ci)
    const float* __restrict__ bias,
    unsigned short* __restrict__ h)          // [16][2048][256] bf16 (s-padded rows)
{
  __shared__ unsigned short sX[18432];       // 36 KB x-window
  __shared__ unsigned short sB[2][4096];     // 2 x 8 KB weight chunk, chunk-swizzled
  const int tid = threadIdx.x;
  const int w = tid >> 6, lane = tid & 63, quad = lane >> 4, l16 = lane & 15;
  const int n  = blockIdx.y;
  const int s0 = blockIdx.x * 128;
  const int d0 = blockIdx.z * 128;

  {
    const unsigned short* xbase = xt + ((size_t)n * LIN + s0) * XTS;
    #pragma unroll
    for (int i = 0; i < 9; ++i) {
      int u = i * 256 + tid;
      gld16(xbase + u * 8, ((char*)sX) + u * 16);
    }
  }

  const int brow0 = tid >> 2, bkgs = tid & 3;
  short8 breg[2];
  #pragma unroll
  for (int i2 = 0; i2 < 2; ++i2) {
    int row = i2 * 64 + brow0;
    int kg = bkgs ^ ((row >> 1) & 3);
    breg[i2] = *(const short8*)(wb + (size_t)(d0 + row) * 1024 + kg * 8);
  }
  #pragma unroll
  for (int i2 = 0; i2 < 2; ++i2)
    *(short8*)(&sB[0][(i2 * 256 + tid) * 8]) = breg[i2];
  __syncthreads();                          // full drain once (X DMA + sB[0])

  f32x4 acc[2][8];
  #pragma unroll
  for (int i = 0; i < 2; ++i)
    #pragma unroll
    for (int j = 0; j < 8; ++j) acc[i][j] = (f32x4){0.f, 0.f, 0.f, 0.f};

  for (int kc = 0; kc < 32; ++kc) {
    const int kcn = (kc < 31) ? kc + 1 : kc;
    const int kpn = kcn >> 2, ci0n = (kcn & 3) * 32;
    #pragma unroll
    for (int i2 = 0; i2 < 2; ++i2) {
      int row = i2 * 64 + brow0;
      int kg = bkgs ^ ((row >> 1) & 3);
      breg[i2] = *(const short8*)(wb + (size_t)(d0 + row) * 1024 + kpn * 128 + ci0n + kg * 8);
    }

    const int kp = kc >> 2, ci0 = (kc & 3) * 32;
    const unsigned short* sBc = sB[kc & 1];
    short8 bfr[8];
    #pragma unroll
    for (int j = 0; j < 8; ++j) {
      int r = j * 16 + l16;
      bfr[j] = *(const short8*)(sBc + r * 32 + (quad ^ ((r >> 1) & 3)) * 8);
    }
    #pragma unroll
    for (int i = 0; i < 2; ++i) {
      int srow = w * 32 + i * 16 + l16;
      short8 afr = *(const short8*)(sX + (srow + kp) * XTS + ci0 + quad * 8);
      #pragma unroll
      for (int j = 0; j < 8; ++j)
        acc[i][j] = __builtin_amdgcn_mfma_f32_16x16x32_bf16(afr, bfr[j], acc[i][j], 0, 0, 0);
    }

    #pragma unroll
    for (int i2 = 0; i2 < 2; ++i2)
      *(short8*)(&sB[(kc + 1) & 1][(i2 * 256 + tid) * 8]) = breg[i2];
    sync_lds();
  }

  #pragma unroll
  for (int i = 0; i < 2; ++i)
    #pragma unroll
    for (int j = 0; j < 8; ++j) {
      int col = d0 + j * 16 + l16;
      float bv = bias[col];
      #pragma unroll
      for (int jj = 0; jj < 4; ++jj) {
        int s = s0 + w * 32 + i * 16 + quad * 4 + jj;
        if (s < SL) {
          float val = fmaxf(acc[i][j][jj] + bv, 0.f);
          h[(size_t)(n * 2048 + s) * CO + col] = f2bf(val);
        }
      }
    }
}

// ---------------- q/k/v linear GEMMs: reg-prefetch dbuf; z==2 LDS-transpose epilogue -------
// Round-6 change: v (z==2) was written as 2B scatter at 64KB stride (64 lines/wave-inst,
// ~64x VMEM request amplification on 16 MB). Now: acc tile -> LDS [col][m] (XOR-swizzled)
// -> 16B dwordx4 stores along ss (rows 8-aligned since M is n*2048+s padded). Tail ss>=SL
// zeroed so attn's PV never reads garbage.
__global__ __launch_bounds__(256) void lin_gemm(
    const unsigned short* __restrict__ A,    // h [16][2048][256]
    const unsigned short* __restrict__ Bq, const unsigned short* __restrict__ Bk,
    const unsigned short* __restrict__ Bv,
    const float* __restrict__ biq, const float* __restrict__ bik,
    const float* __restrict__ biv,
    unsigned short* __restrict__ qb, unsigned short* __restrict__ kb,
    unsigned short* __restrict__ vtb)
{
  __shared__ unsigned short smem[16384];     // 32 KB: sA[2]@0, sB[2]@8192; reused for v-xpose
  unsigned short* const sAb = smem;
  unsigned short* const sBb = smem + 8192;
  const int tid = threadIdx.x;
  const int w = tid >> 6, lane = tid & 63, quad = lane >> 4, l16 = lane & 15;
  const int m0 = blockIdx.x * 128, d0 = blockIdx.y * 128, z = blockIdx.z;
  const unsigned short* B = (z == 0) ? Bq : (z == 1) ? Bk : Bv;
  const float* bias        = (z == 0) ? biq : (z == 1) ? bik : biv;

  const int brow0 = tid >> 2, bkgs = tid & 3;
  short8 areg[2], breg[2];
  #pragma unroll
  for (int i2 = 0; i2 < 2; ++i2) {
    int row = i2 * 64 + brow0;
    int kg = bkgs ^ ((row >> 1) & 3);
    areg[i2] = *(const short8*)(A + (size_t)(m0 + row) * CO + kg * 8);
    breg[i2] = *(const short8*)(B + (size_t)(d0 + row) * CO + kg * 8);
  }
  #pragma unroll
  for (int i2 = 0; i2 < 2; ++i2) {
    *(short8*)(sAb + (i2 * 256 + tid) * 8) = areg[i2];
    *(short8*)(sBb + (i2 * 256 + tid) * 8) = breg[i2];
  }
  sync_lds();

  f32x4 acc[2][8];
  #pragma unroll
  for (int i = 0; i < 2; ++i)
    #pragma unroll
    for (int j = 0; j < 8; ++j) acc[i][j] = (f32x4){0.f, 0.f, 0.f, 0.f};

  for (int kc = 0; kc < 8; ++kc) {
    const int kcn = (kc < 7) ? kc + 1 : kc;
    #pragma unroll
    for (int i2 = 0; i2 < 2; ++i2) {
      int row = i2 * 64 + brow0;
      int kg = bkgs ^ ((row >> 1) & 3);
      areg[i2] = *(const short8*)(A + (size_t)(m0 + row) * CO + kcn * 32 + kg * 8);
      breg[i2] = *(const short8*)(B + (size_t)(d0 + row) * CO + kcn * 32 + kg * 8);
    }

    const unsigned short* sAc = sAb + (kc & 1) * 4096;
    const unsigned short* sBc = sBb + (kc & 1) * 4096;
    short8 afr[2], bfr[8];
    #pragma unroll
    for (int i = 0; i < 2; ++i) {
      int r = w * 32 + i * 16 + l16;
      afr[i] = *(const short8*)(sAc + r * 32 + (quad ^ ((r >> 1) & 3)) * 8);
    }
    #pragma unroll
    for (int j = 0; j < 8; ++j) {
      int r = j * 16 + l16;
      bfr[j] = *(const short8*)(sBc + r * 32 + (quad ^ ((r >> 1) & 3)) * 8);
    }
    #pragma unroll
    for (int i = 0; i < 2; ++i)
      #pragma unroll
      for (int j = 0; j < 8; ++j)
        acc[i][j] = __builtin_amdgcn_mfma_f32_16x16x32_bf16(afr[i], bfr[j], acc[i][j], 0, 0, 0);

    #pragma unroll
    for (int i2 = 0; i2 < 2; ++i2) {
      *(short8*)(sAb + ((kc + 1) & 1) * 4096 + (i2 * 256 + tid) * 8) = areg[i2];
      *(short8*)(sBb + ((kc + 1) & 1) * 4096 + (i2 * 256 + tid) * 8) = breg[i2];
    }
    sync_lds();                              // final iter: all LDS reads drained -> smem free
  }

  if (z < 2) {
    #pragma unroll
    for (int i = 0; i < 2; ++i)
      #pragma unroll
      for (int j = 0; j < 8; ++j) {
        int col = d0 + j * 16 + l16;
        float bv = bias[col];
        #pragma unroll
        for (int jj = 0; jj < 4; ++jj) {
          int m = m0 + w * 32 + i * 16 + quad * 4 + jj;
          float val = acc[i][j][jj] + bv;
          ((z == 0) ? qb : kb)[(size_t)m * CO + col] = f2bf(val);
        }
      }
  } else {
    // ---- v: transpose through LDS, coalesced 16B stores ----
    // write smem[c][m ^ ((c&7)<<3)] (swizzle kills the 256B-row bank period)
    #pragma unroll
    for (int i = 0; i < 2; ++i)
      #pragma unroll
      for (int j = 0; j < 8; ++j) {
        int c = j * 16 + l16;
        float bv = bias[d0 + c];
        int mb = w * 32 + i * 16 + quad * 4;
        u16x4 pk;
        #pragma unroll
        for (int jj = 0; jj < 4; ++jj) pk[jj] = f2bf(acc[i][j][jj] + bv);
        *(u16x4*)(smem + c * 128 + (mb ^ ((c & 7) << 3))) = pk;
      }
    sync_lds();
    // thread t: col = t>>1, m-half = (t&1)*64; block lies in ONE n (m0 % 2048 multiple of 128)
    const int c = tid >> 1, mh = (tid & 1) * 64;
    const int nn = m0 >> 11;
    const int sbase = (m0 & 2047) + mh;
    unsigned short* vrow = vtb + (size_t)(d0 + c) * MP + nn * 2048;
    #pragma unroll
    for (int b = 0; b < 8; ++b) {
      int ss = sbase + b * 8;
      short8 val = *(const short8*)(smem + c * 128 + ((mh + b * 8) ^ ((c & 7) << 3)));
      if (ss + 7 >= SL) {                    // zero tail rows (PV NaN guard)
        #pragma unroll
        for (int e = 0; e < 8; ++e)
          if (ss + e >= SL) val[e] = 0;
      }
      *(short8*)(vrow + ss) = val;           // 16B-aligned: ss multiple of 8
    }
  }
}

// ---------------- fused sigmoid attention: round-5 verbatim (103.5 us), padded-row bases ----
// grid 256, 512 threads = 8 waves (sr=w&3 s-range, tr=w>>2 t/d-half), s-tile 128, t-tile 64.
// LDS (144 KB): sK[2] 64 KB, sV[2] 64 KB, sP 16 KB. 3 rendezvous/iter, vmcnt(8) counted wait.
// [Box notes r1-r6: in-reg P spills (256-reg cap @2 w/SIMD); 1-wave/SIMD shapes latency-bound;
//  deferred-PV 1-barrier regressed. This structure is the basin floor ~103 us.]
__global__ __launch_bounds__(512, 2) void attn_kernel(
    const unsigned short* __restrict__ qb,   // [16][2048][256]
    const unsigned short* __restrict__ kb,   // [16][2048][256]
    const unsigned short* __restrict__ vtb,  // [256][16][2048]
    float* __restrict__ out)                 // [16][256][2041]
{
  __shared__ unsigned short sK[2][16384];    // 2 x 32 KB
  __shared__ unsigned short sV[2][16384];    // 2 x 32 KB
  __shared__ unsigned short sP[8192];        // 16 KB
  const int tid = threadIdx.x;
  const int w = tid >> 6, lane = tid & 63;
  const int half = lane >> 5, l32 = lane & 31;
  const int bidx = blockIdx.x;
  const int n = (bidx & 7) + ((bidx >> 7) << 3);   // XCD-pinned: 2 n's per XCD
  const int s0 = ((bidx >> 3) & 15) * 128;
  const int sr = w & 3, tr = w >> 2;         // tr doubles as d-half in PV

  const unsigned short* kbN = kb + (size_t)(n * 2048) * CO;
  const unsigned short* vbN = vtb + (size_t)n * 2048;

#define STAGE_TILE(buf, tk)                                                      \
  {                                                                              \
    _Pragma("unroll")                                                            \
    for (int i = 0; i < 4; ++i) {                                                \
      int u = i * 512 + tid;                                                     \
      int t = u >> 5, sl = u & 31;                                               \
      gld16(kbN + (size_t)((tk) + t) * CO + ((sl ^ (t & 31)) << 3),              \
            ((char*)sK[buf]) + u * 16);                                          \
    }                                                                            \
    _Pragma("unroll")                                                            \
    for (int i = 0; i < 4; ++i) {                                                \
      int u = i * 512 + tid;                                                     \
      int d = u >> 3, sl = u & 7;                                                \
      gld16(vbN + (size_t)d * MP + (tk) + ((sl ^ (d & 7)) << 3),                 \
            ((char*)sV[buf]) + u * 16);                                          \
    }                                                                            \
  }

  STAGE_TILE(0, 0)

  // Q frags (B-operand): element (s = s0+sr*32+l32, c = kk*16+half*8+j)
  short8 qf[16];
  {
    const unsigned short* qp = qb + (size_t)(n * 2048 + s0 + sr * 32 + l32) * CO + half * 8;
    #pragma unroll
    for (int kk = 0; kk < 16; ++kk) qf[kk] = *(const short8*)(qp + kk * 16);
  }

  __builtin_amdgcn_s_waitcnt(0x0F70);        // vmcnt(0): tile0 + Q resident
  barrier_only();

  f32x16 o[4];
  #pragma unroll
  for (int di = 0; di < 4; ++di)
    #pragma unroll
    for (int r = 0; r < 16; ++r) o[di][r] = 0.f;

  for (int it = 0; it < 32; ++it) {
    const int cur = it & 1;
    if (it < 31) {
      STAGE_TILE(cur ^ 1, (it + 1) * 64)
      __builtin_amdgcn_s_waitcnt(0x0F78);    // vmcnt(8): wait only tile-it's 8 DMA insts
    } else {
      __builtin_amdgcn_s_waitcnt(0x0F70);    // last tile
    }
    barrier_only();                          // all waves' tile-it DMA complete

    // QK^T as mfma(kf, qf): A rows = t, B cols = s  =>  C col = s (lane), rows = t
    const unsigned short* sKc = sK[cur];
    const int tl = tr * 32 + l32;
    f32x16 sacc;
    #pragma unroll
    for (int r = 0; r < 16; ++r) sacc[r] = 0.f;
    #pragma unroll
    for (int kk = 0; kk < 16; ++kk) {
      short8 kf = *(const short8*)(sKc + tl * 256 + (((kk * 2 + half) ^ (tl & 31)) << 3));
      sacc = __builtin_amdgcn_mfma_f32_32x32x16_bf16(kf, qf[kk], sacc, 0, 0, 0);
    }

    // sigmoid + packed b64 P-write: quad q2 -> 4 consecutive t at fixed s
    const int t0 = it * 64;
    #pragma unroll
    for (int q2 = 0; q2 < 4; ++q2) {
      u16x4 pk;
      #pragma unroll
      for (int e = 0; e < 4; ++e) {
        int tg = t0 + tr * 32 + 8 * q2 + 4 * half + e;
        float p = __builtin_amdgcn_rcpf(1.f + __expf(-sacc[q2 * 4 + e] * 0.0625f));
        pk[e] = (tg < SL) ? f2bf(p) : (unsigned short)0;
      }
      *(u16x4*)(sP + ((tr * 4 + q2) * 128 + sr * 32 + l32) * 8 + 4 * half) = pk;
    }
    sync_lds();                              // sP complete; sK[cur] reads done

    // P·V as mfma(vf, pa): A rows = d, B cols = s  =>  C col = s, rows = d
    const unsigned short* sVc = sV[cur];
    #pragma unroll
    for (int kt = 0; kt < 4; ++kt) {
      int g = kt * 2 + half;
      short8 pa = *(const short8*)(sP + ((g << 7) + sr * 32 + l32) * 8);
      #pragma unroll
      for (int di = 0; di < 4; ++di) {
        int d = tr * 128 + di * 32 + l32;
        short8 vf = *(const short8*)(sVc + d * 64 + ((g ^ (d & 7)) << 3));
        o[di] = __builtin_amdgcn_mfma_f32_32x32x16_bf16(vf, pa, o[di], 0, 0, 0);
      }
    }
    sync_lds();                              // sV[cur]/sP reads done -> safe to overwrite
  }

  // store: C col = s = s0+sr*32+l32 (coalesced 32-lane runs), rows = d
  const int s = s0 + sr * 32 + l32;
  if (s < SL) {
    float* op = out + (size_t)n * CO * SL + s;
    #pragma unroll
    for (int di = 0; di < 4; ++di)
      #pragma unroll
      for (int r = 0; r < 16; ++r) {
        int d = tr * 128 + di * 32 + (r & 3) + 8 * (r >> 2) + 4 * half;
        __builtin_nontemporal_store(o[di][r], op + (size_t)d * SL);
      }
  }
#undef STAGE_TILE
}

extern "C" void kernel_launch(void* const* d_in, const int* in_sizes, int n_in,
                              void* d_out, int out_size, void* d_ws, size_t ws_size,
                              hipStream_t stream) {
  const float* x      = (const float*)d_in[0];
  const float* conv_w = (const float*)d_in[1];
  const float* conv_b = (const float*)d_in[2];
  const float* wq     = (const float*)d_in[3];
  const float* bq     = (const float*)d_in[4];
  const float* wk     = (const float*)d_in[5];
  const float* bk     = (const float*)d_in[6];
  const float* wv     = (const float*)d_in[7];
  const float* bv     = (const float*)d_in[8];

  char* ws = (char*)d_ws;
  unsigned short* xt  = (unsigned short*)(ws + XT_OFF);
  unsigned short* cw  = (unsigned short*)(ws + CW_OFF);
  unsigned short* wqb = (unsigned short*)(ws + WQ_OFF);
  unsigned short* wkb = (unsigned short*)(ws + WK_OFF);
  unsigned short* wvb = (unsigned short*)(ws + WV_OFF);
  unsigned short* hb  = (unsigned short*)(ws + H_OFF);
  unsigned short* qb  = (unsigned short*)(ws + Q_OFF);
  unsigned short* kb  = (unsigned short*)(ws + K_OFF);
  unsigned short* vtb = (unsigned short*)(ws + VT_OFF);

  hipLaunchKernelGGL(prep_kernel, dim3(4096 + 1024 + 192), dim3(256), 0, stream,
                     x, xt, conv_w, cw, wq, wk, wv, wqb, wkb, wvb);
  hipLaunchKernelGGL(conv_gemm, dim3(16, 16, 2), dim3(256), 0, stream, xt, cw, conv_b, hb);
  hipLaunchKernelGGL(lin_gemm,  dim3(256, 2, 3), dim3(256), 0, stream,
                     hb, wqb, wkb, wvb, bq, bk, bv, qb, kb, vtb);
  hipLaunchKernelGGL(attn_kernel, dim3(256), dim3(512), 0, stream,
                     qb, kb, vtb, (float*)d_out);
}

// Round 8
// 230.273 us; speedup vs baseline: 1.1081x; 1.0138x over previous
//
#include <hip/hip_runtime.h>

typedef short short8 __attribute__((ext_vector_type(8)));
typedef float f32x4 __attribute__((ext_vector_type(4)));
typedef float f32x16 __attribute__((ext_vector_type(16)));
typedef unsigned short u16x4 __attribute__((ext_vector_type(4)));

constexpr int NB = 16, CIN = 128, LIN = 2048, CO = 256;
constexpr int SL = 2041;                 // output sequence length
constexpr int MP = 32768;                // padded rows = 16 * 2048
constexpr int XTS = 136;                 // xT row stride (elems): 16B-aligned
constexpr int QSTR = 2048 * CO + 256;    // q/k per-n stride (elems): +512B skew de-aliases 1MiB pow2

// Row convention: within n, row s in [0,2048); rows [SL,2048) are garbage and masked:
//   - K garbage -> sigmoid -> P forced 0 by (tg < SL) ternary
//   - vtb tail ss in [SL,2048) explicitly zeroed at write
//   - q rows >= SL never read

// ---- workspace layout (bytes, all 256-aligned) ----
constexpr size_t XT_OFF = 0;
constexpr size_t XT_SZ  = (size_t)NB*LIN*XTS*2 + 65536;
constexpr size_t CW_OFF = XT_OFF + XT_SZ;
constexpr size_t CW_SZ  = (size_t)CO*CIN*8*2;            // conv_w bf16 [256][1024]
constexpr size_t WQ_OFF = CW_OFF + CW_SZ;
constexpr size_t WB_SZ  = (size_t)CO*CO*2;
constexpr size_t WK_OFF = WQ_OFF + WB_SZ;
constexpr size_t WV_OFF = WK_OFF + WB_SZ;
constexpr size_t Q_OFF  = WV_OFF + WB_SZ;
constexpr size_t QK_SZ  = (size_t)NB*QSTR*2 + 256;       // 16 MB + skew slack
constexpr size_t K_OFF  = Q_OFF + QK_SZ;
constexpr size_t VT_OFF = K_OFF + QK_SZ;                 // v transposed [256][16][2048]

__device__ inline unsigned short f2bf(float f) {
  union { float f; unsigned int u; } v; v.f = f;
  unsigned int r = v.u + 0x7fffu + ((v.u >> 16) & 1u);
  return (unsigned short)(r >> 16);
}

// CK-style LDS barrier: waits only lgkmcnt(0) (ds ops), does NOT drain vmcnt.
__device__ inline void sync_lds() {
  __asm__ volatile("" ::: "memory");
  __builtin_amdgcn_s_waitcnt(0xc07f);   // lgkmcnt(0)
  __builtin_amdgcn_s_barrier();
  __asm__ volatile("" ::: "memory");
}
__device__ inline void barrier_only() {
  __asm__ volatile("" ::: "memory");
  __builtin_amdgcn_s_barrier();
  __asm__ volatile("" ::: "memory");
}

#if defined(__has_builtin)
#if __has_builtin(__builtin_amdgcn_global_load_lds)
#define HAVE_GLDS 1
#endif
#endif

__device__ inline void gld16(const unsigned short* g, void* l) {
#ifdef HAVE_GLDS
  __builtin_amdgcn_global_load_lds(
      (const __attribute__((address_space(1))) void*)g,
      (__attribute__((address_space(3))) void*)l, 16, 0, 0);
#else
  *(short8*)l = *(const short8*)g;
#endif
}

// ---------------- fused prep: xpose (4096 blk) + wconv (1024 blk) + wqkv (192 blk) ---------
__global__ __launch_bounds__(256) void prep_kernel(
    const float* __restrict__ x, unsigned short* __restrict__ xt,
    const float* __restrict__ cw_in, unsigned short* __restrict__ cw_out,
    const float* __restrict__ wq, const float* __restrict__ wk, const float* __restrict__ wv,
    unsigned short* __restrict__ wqb, unsigned short* __restrict__ wkb,
    unsigned short* __restrict__ wvb) {
  __shared__ float tile[32][33];
  const int b = blockIdx.x;
  const int tid = threadIdx.x;
  if (b < 4096) {
    const int tx = tid & 31, ty = tid >> 5;
    const int s0 = (b & 63) * 32, c0 = ((b >> 6) & 3) * 32, n = b >> 8;
    #pragma unroll
    for (int r = 0; r < 4; ++r)
      tile[ty * 4 + r][tx] = x[((size_t)(n * CIN + c0 + ty * 4 + r)) * LIN + s0 + tx];
    __syncthreads();
    #pragma unroll
    for (int r = 0; r < 4; ++r)
      xt[((size_t)(n * LIN + s0 + ty * 4 + r)) * XTS + c0 + tx] = f2bf(tile[tx][ty * 4 + r]);
  } else if (b < 4096 + 1024) {
    int idx = (b - 4096) * 256 + tid;
    int co = idx >> 10, r = idx & 1023, kp = r >> 7, ci = r & 127;
    cw_out[idx] = f2bf(cw_in[co * 1024 + ci * 8 + kp]);
  } else {
    int lb2 = b - (4096 + 1024);
    int z = lb2 >> 6, lb = lb2 & 63;
    const float* src = (z == 0) ? wq : (z == 1) ? wk : wv;
    unsigned short* dst = (z == 0) ? wqb : (z == 1) ? wkb : wvb;
    int i = (lb * 256 + tid) * 4;
    float4 v = *(const float4*)(src + i);
    u16x4 r;
    r.x = f2bf(v.x); r.y = f2bf(v.y); r.z = f2bf(v.z); r.w = f2bf(v.w);
    *(u16x4*)(dst + i) = r;
  }
}

// ---------------- fused conv + q/k/v: h never leaves LDS ----------------
// grid (16 s-tiles, 16 n), 512 thr = 8 waves (sg = w>>1 s-group of 32, dh = w&1 d/dout-half).
// LDS 132 KB: hL 64 KB ([128 m][256 k] in lin-sA swizzled layout; reused for v-transpose),
//             sX 36 KB x-window, sB[2] 32 KB weight chunk dbuf (256 rows x 32 k).
// Phase 1 = conv loop (K=1024, 32 kc) -> relu+bias -> hL. Phase 2 = 3x lin kc-loop (K=256,
// 8 kc) with A from hL. Saves vs split kernels: h 16MB write + 48MB read + 1 launch gap.
__global__ __launch_bounds__(512, 2) void conv_qkv(
    const unsigned short* __restrict__ xt,   // [16][2048][136] bf16
    const unsigned short* __restrict__ wb,   // conv w [256][1024] bf16
    const float* __restrict__ cbias,
    const unsigned short* __restrict__ Bq, const unsigned short* __restrict__ Bk,
    const unsigned short* __restrict__ Bv,
    const float* __restrict__ biq, const float* __restrict__ bik,
    const float* __restrict__ biv,
    unsigned short* __restrict__ qb, unsigned short* __restrict__ kb,
    unsigned short* __restrict__ vtb)
{
  __shared__ unsigned short hL[32768];       // 64 KB
  __shared__ unsigned short sX[18432];       // 36 KB
  __shared__ unsigned short sB[2][8192];     // 2 x 16 KB
  const int tid = threadIdx.x;
  const int w = tid >> 6, lane = tid & 63, quad = lane >> 4, l16 = lane & 15;
  const int sg = w >> 1, dh = w & 1;
  const int n = blockIdx.y, s0 = blockIdx.x * 128;

  // ---- stage x window (2304 x 16B) ----
  {
    const unsigned short* xbase = xt + ((size_t)n * LIN + s0) * XTS;
    #pragma unroll
    for (int i = 0; i < 5; ++i) {
      int u = i * 512 + tid;
      if (u < 2304) gld16(xbase + u * 8, ((char*)sX) + u * 16);
    }
  }

  const int brow0 = tid >> 2, bkgs = tid & 3;   // brow0 0..127
  short8 breg[2];
  #pragma unroll
  for (int i2 = 0; i2 < 2; ++i2) {
    int row = i2 * 128 + brow0;
    int kg = bkgs ^ ((row >> 1) & 3);
    breg[i2] = *(const short8*)(wb + (size_t)row * 1024 + kg * 8);
  }
  #pragma unroll
  for (int i2 = 0; i2 < 2; ++i2)
    *(short8*)(&sB[0][(i2 * 512 + tid) * 8]) = breg[i2];
  __syncthreads();                          // full drain once (X DMA + sB[0])

  f32x4 acc[2][8];
  #pragma unroll
  for (int i = 0; i < 2; ++i)
    #pragma unroll
    for (int j = 0; j < 8; ++j) acc[i][j] = (f32x4){0.f, 0.f, 0.f, 0.f};

  // ---- phase 1: conv, 32 kc of 32 k ----
  for (int kc = 0; kc < 32; ++kc) {
    const int kcn = (kc < 31) ? kc + 1 : kc;
    const int kpn = kcn >> 2, ci0n = (kcn & 3) * 32;
    #pragma unroll
    for (int i2 = 0; i2 < 2; ++i2) {
      int row = i2 * 128 + brow0;
      int kg = bkgs ^ ((row >> 1) & 3);
      breg[i2] = *(const short8*)(wb + (size_t)row * 1024 + kpn * 128 + ci0n + kg * 8);
    }

    const int kp = kc >> 2, ci0 = (kc & 3) * 32;
    const unsigned short* sBc = sB[kc & 1];
    short8 bfr[8];
    #pragma unroll
    for (int j = 0; j < 8; ++j) {
      int r = dh * 128 + j * 16 + l16;
      bfr[j] = *(const short8*)(sBc + r * 32 + (quad ^ ((r >> 1) & 3)) * 8);
    }
    #pragma unroll
    for (int i = 0; i < 2; ++i) {
      int srow = sg * 32 + i * 16 + l16;
      short8 afr = *(const short8*)(sX + (srow + kp) * XTS + ci0 + quad * 8);
      #pragma unroll
      for (int j = 0; j < 8; ++j)
        acc[i][j] = __builtin_amdgcn_mfma_f32_16x16x32_bf16(afr, bfr[j], acc[i][j], 0, 0, 0);
    }

    #pragma unroll
    for (int i2 = 0; i2 < 2; ++i2)
      *(short8*)(&sB[(kc + 1) & 1][(i2 * 512 + tid) * 8]) = breg[i2];
    sync_lds();
  }

  // ---- h epilogue -> hL in lin-sA swizzled layout: addr(r,c) = r*256 + (c>>5)*32
  //      + (((c>>3)&3) ^ ((r>>1)&3))*8 + (c&7) ----
  #pragma unroll
  for (int i = 0; i < 2; ++i)
    #pragma unroll
    for (int j = 0; j < 8; ++j) {
      int c = dh * 128 + j * 16 + l16;
      float bv = cbias[c];
      int cc = (c >> 5) * 32 + (c & 7);
      int g = (c >> 3) & 3;
      #pragma unroll
      for (int jj = 0; jj < 4; ++jj) {
        int r = sg * 32 + i * 16 + quad * 4 + jj;
        hL[r * 256 + cc + ((g ^ ((r >> 1) & 3)) << 3)] =
            f2bf(fmaxf(acc[i][j][jj] + bv, 0.f));
      }
    }

  // ---- phase 2: q/k/v GEMMs, A = hL ----
  for (int z = 0; z < 3; ++z) {
    const unsigned short* B = (z == 0) ? Bq : (z == 1) ? Bk : Bv;
    const float* bias        = (z == 0) ? biq : (z == 1) ? bik : biv;

    #pragma unroll
    for (int i2 = 0; i2 < 2; ++i2) {
      int row = i2 * 128 + brow0;
      int kg = bkgs ^ ((row >> 1) & 3);
      breg[i2] = *(const short8*)(B + (size_t)row * CO + kg * 8);
    }
    #pragma unroll
    for (int i2 = 0; i2 < 2; ++i2)
      *(short8*)(&sB[0][(i2 * 512 + tid) * 8]) = breg[i2];
    sync_lds();                              // hL (z=0) / prior-z reads complete; sB[0] ready

    #pragma unroll
    for (int i = 0; i < 2; ++i)
      #pragma unroll
      for (int j = 0; j < 8; ++j) acc[i][j] = (f32x4){0.f, 0.f, 0.f, 0.f};

    for (int kc = 0; kc < 8; ++kc) {
      const int kcn = (kc < 7) ? kc + 1 : kc;
      #pragma unroll
      for (int i2 = 0; i2 < 2; ++i2) {
        int row = i2 * 128 + brow0;
        int kg = bkgs ^ ((row >> 1) & 3);
        breg[i2] = *(const short8*)(B + (size_t)row * CO + kcn * 32 + kg * 8);
      }

      const unsigned short* sBc = sB[kc & 1];
      short8 afr[2], bfr[8];
      #pragma unroll
      for (int i = 0; i < 2; ++i) {
        int r = sg * 32 + i * 16 + l16;
        afr[i] = *(const short8*)(hL + r * 256 + kc * 32 + (quad ^ ((r >> 1) & 3)) * 8);
      }
      #pragma unroll
      for (int j = 0; j < 8; ++j) {
        int r = dh * 128 + j * 16 + l16;
        bfr[j] = *(const short8*)(sBc + r * 32 + (quad ^ ((r >> 1) & 3)) * 8);
      }
      #pragma unroll
      for (int i = 0; i < 2; ++i)
        #pragma unroll
        for (int j = 0; j < 8; ++j)
          acc[i][j] = __builtin_amdgcn_mfma_f32_16x16x32_bf16(afr[i], bfr[j], acc[i][j], 0, 0, 0);

      #pragma unroll
      for (int i2 = 0; i2 < 2; ++i2)
        *(short8*)(&sB[(kc + 1) & 1][(i2 * 512 + tid) * 8]) = breg[i2];
      sync_lds();                            // also drains hL reads on final kc
    }

    if (z < 2) {
      unsigned short* base = ((z == 0) ? qb : kb) + (size_t)n * QSTR + (size_t)s0 * CO;
      #pragma unroll
      for (int i = 0; i < 2; ++i)
        #pragma unroll
        for (int j = 0; j < 8; ++j) {
          int c = dh * 128 + j * 16 + l16;
          float bv = bias[c];
          #pragma unroll
          for (int jj = 0; jj < 4; ++jj) {
            int r = sg * 32 + i * 16 + quad * 4 + jj;
            base[(size_t)r * CO + c] = f2bf(acc[i][j][jj] + bv);
          }
        }
    } else {
      // ---- v: transpose via hL (free: all hL reads drained), coalesced 16B stores ----
      #pragma unroll
      for (int i = 0; i < 2; ++i)
        #pragma unroll
        for (int j = 0; j < 8; ++j) {
          int c = dh * 128 + j * 16 + l16;
          float bv = bias[c];
          int mb = sg * 32 + i * 16 + quad * 4;
          u16x4 pk;
          #pragma unroll
          for (int jj = 0; jj < 4; ++jj) pk[jj] = f2bf(acc[i][j][jj] + bv);
          *(u16x4*)(hL + c * 128 + (mb ^ ((c & 7) << 3))) = pk;
        }
      sync_lds();
      const int c = tid >> 1, mh = (tid & 1) * 64;
      unsigned short* vrow = vtb + (size_t)c * MP + n * 2048 + s0;
      #pragma unroll
      for (int b = 0; b < 8; ++b) {
        int ml = mh + b * 8;
        int ss = s0 + ml;
        short8 val = *(const short8*)(hL + c * 128 + (ml ^ ((c & 7) << 3)));
        if (ss + 7 >= SL) {                  // zero tail rows (PV NaN guard)
          #pragma unroll
          for (int e = 0; e < 8; ++e)
            if (ss + e >= SL) val[e] = 0;
        }
        *(short8*)(vrow + ml) = val;         // 16B-aligned
      }
    }
  }
}

// ---------------- fused sigmoid attention: round-5 structure (basin floor ~104 us) ----------
// grid 256, 512 threads = 8 waves (sr=w&3 s-range, tr=w>>2 t/d-half), s-tile 128, t-tile 64.
// LDS (144 KB): sK[2] 64 KB, sV[2] 64 KB, sP 16 KB. 3 rendezvous/iter, vmcnt(8) counted wait.
// q/k bases use QSTR skew (de-alias the 1MiB pow2 n-stride, round-7 regression suspect).
__global__ __launch_bounds__(512, 2) void attn_kernel(
    const unsigned short* __restrict__ qb,   // [16][QSTR]
    const unsigned short* __restrict__ kb,   // [16][QSTR]
    const unsigned short* __restrict__ vtb,  // [256][16][2048]
    float* __restrict__ out)                 // [16][256][2041]
{
  __shared__ unsigned short sK[2][16384];    // 2 x 32 KB
  __shared__ unsigned short sV[2][16384];    // 2 x 32 KB
  __shared__ unsigned short sP[8192];        // 16 KB
  const int tid = threadIdx.x;
  const int w = tid >> 6, lane = tid & 63;
  const int half = lane >> 5, l32 = lane & 31;
  const int bidx = blockIdx.x;
  const int n = (bidx & 7) + ((bidx >> 7) << 3);   // XCD-pinned: 2 n's per XCD
  const int s0 = ((bidx >> 3) & 15) * 128;
  const int sr = w & 3, tr = w >> 2;         // tr doubles as d-half in PV

  const unsigned short* kbN = kb + (size_t)n * QSTR;
  const unsigned short* vbN = vtb + (size_t)n * 2048;

#define STAGE_TILE(buf, tk)                                                      \
  {                                                                              \
    _Pragma("unroll")                                                            \
    for (int i = 0; i < 4; ++i) {                                                \
      int u = i * 512 + tid;                                                     \
      int t = u >> 5, sl = u & 31;                                               \
      gld16(kbN + (size_t)((tk) + t) * CO + ((sl ^ (t & 31)) << 3),              \
            ((char*)sK[buf]) + u * 16);                                          \
    }                                                                            \
    _Pragma("unroll")                                                            \
    for (int i = 0; i < 4; ++i) {                                                \
      int u = i * 512 + tid;                                                     \
      int d = u >> 3, sl = u & 7;                                                \
      gld16(vbN + (size_t)d * MP + (tk) + ((sl ^ (d & 7)) << 3),                 \
            ((char*)sV[buf]) + u * 16);                                          \
    }                                                                            \
  }

  STAGE_TILE(0, 0)

  // Q frags (B-operand): element (s = s0+sr*32+l32, c = kk*16+half*8+j)
  short8 qf[16];
  {
    const unsigned short* qp = qb + (size_t)n * QSTR
                             + (size_t)(s0 + sr * 32 + l32) * CO + half * 8;
    #pragma unroll
    for (int kk = 0; kk < 16; ++kk) qf[kk] = *(const short8*)(qp + kk * 16);
  }

  __builtin_amdgcn_s_waitcnt(0x0F70);        // vmcnt(0): tile0 + Q resident
  barrier_only();

  f32x16 o[4];
  #pragma unroll
  for (int di = 0; di < 4; ++di)
    #pragma unroll
    for (int r = 0; r < 16; ++r) o[di][r] = 0.f;

  for (int it = 0; it < 32; ++it) {
    const int cur = it & 1;
    if (it < 31) {
      STAGE_TILE(cur ^ 1, (it + 1) * 64)
      __builtin_amdgcn_s_waitcnt(0x0F78);    // vmcnt(8): wait only tile-it's 8 DMA insts
    } else {
      __builtin_amdgcn_s_waitcnt(0x0F70);    // last tile
    }
    barrier_only();                          // all waves' tile-it DMA complete

    // QK^T as mfma(kf, qf): A rows = t, B cols = s  =>  C col = s (lane), rows = t
    const unsigned short* sKc = sK[cur];
    const int tl = tr * 32 + l32;
    f32x16 sacc;
    #pragma unroll
    for (int r = 0; r < 16; ++r) sacc[r] = 0.f;
    #pragma unroll
    for (int kk = 0; kk < 16; ++kk) {
      short8 kf = *(const short8*)(sKc + tl * 256 + (((kk * 2 + half) ^ (tl & 31)) << 3));
      sacc = __builtin_amdgcn_mfma_f32_32x32x16_bf16(kf, qf[kk], sacc, 0, 0, 0);
    }

    // sigmoid + packed b64 P-write: quad q2 -> 4 consecutive t at fixed s
    const int t0 = it * 64;
    #pragma unroll
    for (int q2 = 0; q2 < 4; ++q2) {
      u16x4 pk;
      #pragma unroll
      for (int e = 0; e < 4; ++e) {
        int tg = t0 + tr * 32 + 8 * q2 + 4 * half + e;
        float p = __builtin_amdgcn_rcpf(1.f + __expf(-sacc[q2 * 4 + e] * 0.0625f));
        pk[e] = (tg < SL) ? f2bf(p) : (unsigned short)0;
      }
      *(u16x4*)(sP + ((tr * 4 + q2) * 128 + sr * 32 + l32) * 8 + 4 * half) = pk;
    }
    sync_lds();                              // sP complete; sK[cur] reads done

    // P·V as mfma(vf, pa): A rows = d, B cols = s  =>  C col = s, rows = d
    const unsigned short* sVc = sV[cur];
    #pragma unroll
    for (int kt = 0; kt < 4; ++kt) {
      int g = kt * 2 + half;
      short8 pa = *(const short8*)(sP + ((g << 7) + sr * 32 + l32) * 8);
      #pragma unroll
      for (int di = 0; di < 4; ++di) {
        int d = tr * 128 + di * 32 + l32;
        short8 vf = *(const short8*)(sVc + d * 64 + ((g ^ (d & 7)) << 3));
        o[di] = __builtin_amdgcn_mfma_f32_32x32x16_bf16(vf, pa, o[di], 0, 0, 0);
      }
    }
    sync_lds();                              // sV[cur]/sP reads done -> safe to overwrite
  }

  // store: C col = s = s0+sr*32+l32 (coalesced 32-lane runs), rows = d
  const int s = s0 + sr * 32 + l32;
  if (s < SL) {
    float* op = out + (size_t)n * CO * SL + s;
    #pragma unroll
    for (int di = 0; di < 4; ++di)
      #pragma unroll
      for (int r = 0; r < 16; ++r) {
        int d = tr * 128 + di * 32 + (r & 3) + 8 * (r >> 2) + 4 * half;
        __builtin_nontemporal_store(o[di][r], op + (size_t)d * SL);
      }
  }
#undef STAGE_TILE
}

extern "C" void kernel_launch(void* const* d_in, const int* in_sizes, int n_in,
                              void* d_out, int out_size, void* d_ws, size_t ws_size,
                              hipStream_t stream) {
  const float* x      = (const float*)d_in[0];
  const float* conv_w = (const float*)d_in[1];
  const float* conv_b = (const float*)d_in[2];
  const float* wq     = (const float*)d_in[3];
  const float* bq     = (const float*)d_in[4];
  const float* wk     = (const float*)d_in[5];
  const float* bk     = (const float*)d_in[6];
  const float* wv     = (const float*)d_in[7];
  const float* bv     = (const float*)d_in[8];

  char* ws = (char*)d_ws;
  unsigned short* xt  = (unsigned short*)(ws + XT_OFF);
  unsigned short* cw  = (unsigned short*)(ws + CW_OFF);
  unsigned short* wqb = (unsigned short*)(ws + WQ_OFF);
  unsigned short* wkb = (unsigned short*)(ws + WK_OFF);
  unsigned short* wvb = (unsigned short*)(ws + WV_OFF);
  unsigned short* qb  = (unsigned short*)(ws + Q_OFF);
  unsigned short* kb  = (unsigned short*)(ws + K_OFF);
  unsigned short* vtb = (unsigned short*)(ws + VT_OFF);

  hipLaunchKernelGGL(prep_kernel, dim3(4096 + 1024 + 192), dim3(256), 0, stream,
                     x, xt, conv_w, cw, wq, wk, wv, wqb, wkb, wvb);
  hipLaunchKernelGGL(conv_qkv, dim3(16, 16), dim3(512), 0, stream,
                     xt, cw, conv_b, wqb, wkb, wvb, bq, bk, bv, qb, kb, vtb);
  hipLaunchKernelGGL(attn_kernel, dim3(256), dim3(512), 0, stream,
                     qb, kb, vtb, (float*)d_out);
}